// Round 8
// baseline (182.240 us; speedup 1.0000x reference)
//
#include <hip/hip_runtime.h>
#include <math.h>

#define NN 512
#define BB 16
#define TOTAL (BB * NN * NN)   // 4,194,304 cells
#define EPS_F 1e-5f
#define DELTA_F 0.05f

#define HALO 8
#define LR   80                 // 64 + 2*HALO register tile
#define PT   5                  // cells per thread per dim (80/16)
#define GUARD 16384             // bytes; halo over/under-run is <= 8208 B

// bf16 helpers (storage only; all math in f32)
__device__ __forceinline__ float bf16_ld(unsigned short h) {
    return __uint_as_float((unsigned)h << 16);
}
__device__ __forceinline__ unsigned short bf16_st(float f) {
    unsigned b = __float_as_uint(f);
    return (unsigned short)((b + 0x7FFFu + ((b >> 16) & 1u)) >> 16);  // RNE
}

// lane gets lane-1 (within each 16-lane DPP row); boundary lanes -> 0
__device__ __forceinline__ float dpp_shr1(float x) {
    int r = __builtin_amdgcn_update_dpp(0, __float_as_int(x), 0x111, 0xf, 0xf, true);
    return __int_as_float(r);
}
// lane gets lane+1; boundary lanes -> 0
__device__ __forceinline__ float dpp_shl1(float x) {
    int r = __builtin_amdgcn_update_dpp(0, __float_as_int(x), 0x101, 0xf, 0xf, true);
    return __int_as_float(r);
}

// ---------------------------------------------------------------------------
// Init: u0(bf16) = dir ? bc : 0 ; cmask(u8) = fluid ;
// pre(bf16) = w_outer(i,j) * [geom<=0.5] * (x·w_back + b_back)
// ---------------------------------------------------------------------------
__global__ __launch_bounds__(256) void init_kernel(
    const float* __restrict__ x_mix,
    unsigned short* __restrict__ u,
    unsigned char* __restrict__ cmask,
    unsigned short* __restrict__ pre,
    const float* __restrict__ w_back,
    const float* __restrict__ b_back)
{
    int idx = blockIdx.x * blockDim.x + threadIdx.x;
    if (idx >= TOTAL) return;
    int j = idx & (NN - 1);
    int i = (idx >> 9) & (NN - 1);
    float4 xm = reinterpret_cast<const float4*>(x_mix)[idx];
    bool edge = (i == 0) | (i == NN - 1) | (j == 0) | (j == NN - 1);
    bool dir  = edge || (xm.z > 0.5f);
    cmask[idx] = dir ? 0 : 1;
    u[idx]     = bf16_st(dir ? xm.w : 0.0f);

    float rr = xm.x * w_back[0] + xm.y * w_back[1] + b_back[0];
    float xs = (float)i * (1.0f / 511.0f);
    float ys = (float)j * (1.0f / 511.0f);
    float dd = fminf(fminf(xs, 1.0f - xs), fminf(ys, 1.0f - ys));
    float ww = fminf(fmaxf(dd * (1.0f / DELTA_F), 0.0f), 1.0f);
    if (xm.z > 0.5f) ww = 0.0f;
    pre[idx] = bf16_st(ww * rr);
}

// ---------------------------------------------------------------------------
// Register-tile temporal-blocked stencil, 5x5 cells/thread, bf16 state,
// vectorized LDS-staged I/O. 16x16 threads own an 80x80 tile (64x64 output,
// halo 8 >= ITERS). No load clamping: edge blocks read fictitious (guarded,
// finite) halo data; the in-domain Dirichlet edge rows are frozen and the
// 5-point stencil cannot jump them, so garbage never reaches the interior.
// ---------------------------------------------------------------------------
template<int ITERS, bool FINAL>
__global__ __launch_bounds__(256, 4) void stencil_kernel(
    const unsigned short* __restrict__ uin,
    unsigned short* __restrict__ uout,      // bf16 dest (non-final)
    float* __restrict__ fout,               // f32 dest (final)
    const unsigned char* __restrict__ cmask,
    const unsigned short* __restrict__ pre,
    const float* __restrict__ logit,
    const float* __restrict__ y_mean,
    const float* __restrict__ y_std)
{
    __shared__ float xup[2][PT][256];           // thread row 0 (for tr-1)
    __shared__ float xdn[2][PT][256];           // thread row PT-1 (for tr+1)
    __shared__ __align__(16) char arena[24576]; // staged I/O (phased reuse)

    unsigned short* ustage = (unsigned short*)arena;          // [80*80] u16
    unsigned char*  cstage = (unsigned char*)(arena + 12800); // [80*80] u8
    unsigned short* ostage = (unsigned short*)arena;          // [64*64] u16
    unsigned short* pstage = (unsigned short*)arena;          // [64*64] u16
    float*          fstage = (float*)(arena + 8192);          // [64*64] f32

    const int b   = blockIdx.z;
    const int oy  = blockIdx.y * 64;
    const int ox  = blockIdx.x * 64;
    const int tid = threadIdx.x;
    const int tr  = tid >> 4;
    const int tc  = tid & 15;
    const int R0  = tr * PT;
    const int C0  = tc * PT;

    const size_t slab = (size_t)b * NN * NN;
    const unsigned short* ub = uin + slab;
    const unsigned char*  cb = cmask + slab;

    // ---- cooperative vectorized stage: 80 rows x 10 chunks ----
#pragma unroll
    for (int k0 = 0; k0 < 4; ++k0) {
        int k = tid + k0 * 256;
        if (k < 800) {
            int r = k / 10, c = k - (k / 10) * 10;
            int off = (oy - HALO + r) * NN + (ox - HALO) + c * 8;  // may be <0: guarded
            uint4 v = *(const uint4*)(ub + off);
            *(uint4*)(ustage + r * 80 + c * 8) = v;
            uint2 m = *(const uint2*)(cb + off);
            *(uint2*)(cstage + r * 80 + c * 8) = m;
        }
    }
    __syncthreads();

    // ---- per-thread unpack 5x5 from LDS ----
    float u[PT][PT];
    float cf[PT][PT];   // 1.0 = fluid (update), 0.0 = Dirichlet/frozen
#pragma unroll
    for (int r = 0; r < PT; ++r) {
        int ty = R0 + r;
#pragma unroll
        for (int c = 0; c < PT; ++c) {
            int tx = C0 + c;
            u[r][c] = bf16_ld(ustage[ty * 80 + tx]);
            unsigned m = cstage[ty * 80 + tx];
            bool ring = (ty == 0) | (ty == LR - 1) | (tx == 0) | (tx == LR - 1);
            cf[r][c] = (ring || m == 0u) ? 0.0f : 1.0f;
        }
    }

    const int tup = (tid >= 16)  ? tid - 16 : tid;   // clamped neighbor indices
    const int tdn = (tid < 240)  ? tid + 16 : tid;

    // ---- ITERS fused Jacobi iterations, all in registers ----
#pragma unroll 1
    for (int t = 0; t < ITERS; ++t) {
        const int pb = t & 1;
#pragma unroll
        for (int w = 0; w < PT; ++w) {
            xup[pb][w][tid] = u[0][w];
            xdn[pb][w][tid] = u[PT - 1][w];
        }
        float lsh[PT], rsh[PT];
#pragma unroll
        for (int r = 0; r < PT; ++r) {
            lsh[r] = dpp_shr1(u[r][PT - 1]);
            rsh[r] = dpp_shl1(u[r][0]);
        }
        __syncthreads();
        float th[PT], bh[PT];
#pragma unroll
        for (int w = 0; w < PT; ++w) {
            th[w] = xdn[pb][w][tup];   // garbage for tr==0: ring cf=0 kills it
            bh[w] = xup[pb][w][tdn];   // garbage for tr==15: ring cf=0 kills it
        }
        float prow[PT];
#pragma unroll
        for (int c = 0; c < PT; ++c) prow[c] = th[c];
#pragma unroll
        for (int r = 0; r < PT; ++r) {
            float orow[PT];
#pragma unroll
            for (int c = 0; c < PT; ++c) orow[c] = u[r][c];
#pragma unroll
            for (int c = 0; c < PT; ++c) {
                float up = prow[c];
                float dn = (r < PT - 1) ? u[r + 1][c] : bh[c];
                float lf = (c > 0)      ? orow[c - 1] : lsh[r];
                float rt = (c < PT - 1) ? orow[c + 1] : rsh[r];
                float s  = (up + dn) + (lf + rt);
                float od = orow[c];
                float tq = __builtin_fmaf(0.25f, s, -od);
                u[r][c]  = __builtin_fmaf(cf[r][c], tq, od);
            }
#pragma unroll
            for (int c = 0; c < PT; ++c) prow[c] = orow[c];
        }
    }
    __syncthreads();   // all iters done; arena safe to reuse

    // ---- store center 64x64 (staged, vectorized) ----
    if (!FINAL) {
        // scatter center cells (bf16) to LDS
#pragma unroll
        for (int r = 0; r < PT; ++r) {
            int cy = R0 + r - HALO;
#pragma unroll
            for (int c = 0; c < PT; ++c) {
                int cx = C0 + c - HALO;
                if ((unsigned)cy < 64u && (unsigned)cx < 64u)
                    ostage[cy * 64 + cx] = bf16_st(u[r][c]);
            }
        }
        __syncthreads();
        unsigned short* og = uout + slab;
#pragma unroll
        for (int k0 = 0; k0 < 2; ++k0) {
            int k = tid + k0 * 256;          // 512 chunks of 8 u16
            int r = k >> 3, c = k & 7;
            *(uint4*)(og + (oy + r) * NN + ox + c * 8) =
                *(const uint4*)(ostage + r * 64 + c * 8);
        }
    } else {
        // stage pre (center 64x64, bf16) into LDS
        const unsigned short* pg = pre + slab;
#pragma unroll
        for (int k0 = 0; k0 < 2; ++k0) {
            int k = tid + k0 * 256;          // 512 chunks of 8 u16
            int r = k >> 3, c = k & 7;
            *(uint4*)(pstage + r * 64 + c * 8) =
                *(const uint4*)(pg + (oy + r) * NN + ox + c * 8);
        }
        __syncthreads();
        float rs  = 0.25f / (1.0f + expf(-logit[0]));
        float ym  = y_mean[0];
        float inv = 1.0f / (y_std[0] + EPS_F);
#pragma unroll
        for (int r = 0; r < PT; ++r) {
            int cy = R0 + r - HALO;
#pragma unroll
            for (int c = 0; c < PT; ++c) {
                int cx = C0 + c - HALO;
                if ((unsigned)cy < 64u && (unsigned)cx < 64u) {
                    float e = (u[r][c] - ym) * inv;
                    float p = bf16_ld(pstage[cy * 64 + cx]);
                    fstage[cy * 64 + cx] = __builtin_fmaf(rs, p, e);
                }
            }
        }
        __syncthreads();
        float* og = fout + slab;
#pragma unroll
        for (int k0 = 0; k0 < 4; ++k0) {
            int k = tid + k0 * 256;          // 1024 chunks of 4 f32
            int r = k >> 4, c = k & 15;
            *(uint4*)(og + (oy + r) * NN + ox + c * 4) =
                *(const uint4*)(fstage + r * 64 + c * 4);
        }
    }
}

// ---------------------------------------------------------------------------
extern "C" void kernel_launch(void* const* d_in, const int* in_sizes, int n_in,
                              void* d_out, int out_size, void* d_ws, size_t ws_size,
                              hipStream_t stream)
{
    const float* x_mix  = (const float*)d_in[0];
    const float* w_back = (const float*)d_in[1];
    const float* b_back = (const float*)d_in[2];
    const float* logit  = (const float*)d_in[3];
    const float* y_mean = (const float*)d_in[4];
    const float* y_std  = (const float*)d_in[5];

    float* out = (float*)d_out;

    // Workspace: [GUARD][u_a 2B][cmask 1B][u_b 2B][pre 2B] — halo vector
    // loads may run up to ~8.2 KB past either end of u_a/u_b/cmask; every
    // such access lands in an adjacent defined region or the guard.
    char* ws = (char*)d_ws;
    unsigned short* u_a   = (unsigned short*)(ws + GUARD);
    unsigned char*  cmask = (unsigned char*) (ws + GUARD + (size_t)TOTAL * 2);
    unsigned short* u_b   = (unsigned short*)(ws + GUARD + (size_t)TOTAL * 3);
    unsigned short* pre   = (unsigned short*)(ws + GUARD + (size_t)TOTAL * 5);

    const int block = 256;
    const int grid1d = (TOTAL + block - 1) / block;

    init_kernel<<<grid1d, block, 0, stream>>>(x_mix, u_a, cmask, pre,
                                              w_back, b_back);

    // 50 iters = 6 launches x 8 + 1 launch x 2 (fused epilogue).
    dim3 sgrid(NN / 64, NN / 64, BB);   // 8 x 8 x 16 = 1024 blocks (4/CU)
    stencil_kernel<8, false><<<sgrid, block, 0, stream>>>(u_a, u_b, out, cmask,
        pre, logit, y_mean, y_std);
    stencil_kernel<8, false><<<sgrid, block, 0, stream>>>(u_b, u_a, out, cmask,
        pre, logit, y_mean, y_std);
    stencil_kernel<8, false><<<sgrid, block, 0, stream>>>(u_a, u_b, out, cmask,
        pre, logit, y_mean, y_std);
    stencil_kernel<8, false><<<sgrid, block, 0, stream>>>(u_b, u_a, out, cmask,
        pre, logit, y_mean, y_std);
    stencil_kernel<8, false><<<sgrid, block, 0, stream>>>(u_a, u_b, out, cmask,
        pre, logit, y_mean, y_std);
    stencil_kernel<8, false><<<sgrid, block, 0, stream>>>(u_b, u_a, out, cmask,
        pre, logit, y_mean, y_std);
    stencil_kernel<2, true><<<sgrid, block, 0, stream>>>(u_a, u_b, out, cmask,
        pre, logit, y_mean, y_std);
}

// Round 9
// 131.584 us; speedup vs baseline: 1.3850x; 1.3850x over previous
//
#include <hip/hip_runtime.h>
#include <math.h>

#define NN 512
#define BB 16
#define TOTAL (BB * NN * NN)   // 4,194,304 cells
#define EPS_F 1e-5f
#define DELTA_F 0.05f

#define HALO 8
#define TILE 64                 // register tile (64x64), output 48x48
#define OUT  48
#define PT   4                  // cells per thread per dim (64/16)
#define GUARD 16384             // bytes; halo over/under-run is <= ~8.5 KB

// bf16 helpers (storage only; all math in f32)
__device__ __forceinline__ float bf16_ld(unsigned short h) {
    return __uint_as_float((unsigned)h << 16);
}
__device__ __forceinline__ unsigned short bf16_st(float f) {
    unsigned b = __float_as_uint(f);
    return (unsigned short)((b + 0x7FFFu + ((b >> 16) & 1u)) >> 16);  // RNE
}

// lane gets lane-1 (within each 16-lane DPP row); boundary lanes -> 0
__device__ __forceinline__ float dpp_shr1(float x) {
    int r = __builtin_amdgcn_update_dpp(0, __float_as_int(x), 0x111, 0xf, 0xf, true);
    return __int_as_float(r);
}
// lane gets lane+1; boundary lanes -> 0
__device__ __forceinline__ float dpp_shl1(float x) {
    int r = __builtin_amdgcn_update_dpp(0, __float_as_int(x), 0x101, 0xf, 0xf, true);
    return __int_as_float(r);
}

// ---------------------------------------------------------------------------
// Init (4 cells/thread, vectorized): u0(bf16) = dir ? bc : 0 ;
// cmask(u8) = fluid ; pre(bf16) = w_outer * [geom<=0.5] * (x·w_back + b)
// ---------------------------------------------------------------------------
__global__ __launch_bounds__(256) void init_kernel(
    const float4* __restrict__ xm4,
    unsigned short* __restrict__ u,
    unsigned char* __restrict__ cmask,
    unsigned short* __restrict__ pre,
    const float* __restrict__ w_back,
    const float* __restrict__ b_back)
{
    int g = blockIdx.x * 256 + threadIdx.x;      // 0 .. TOTAL/4-1
    int idx = g * 4;
    int j0 = idx & (NN - 1);
    int i  = (idx >> 9) & (NN - 1);
    float w0 = w_back[0], w1 = w_back[1], bb0 = b_back[0];
    float xs = (float)i * (1.0f / 511.0f);
    float dx = fminf(xs, 1.0f - xs);
    bool iedge = (i == 0) | (i == NN - 1);

    unsigned uw[2] = {0u, 0u};
    unsigned mw = 0u;
    unsigned pw[2] = {0u, 0u};
#pragma unroll
    for (int c = 0; c < 4; ++c) {
        float4 xm = xm4[idx + c];
        int j = j0 + c;
        bool dir = iedge | (j == 0) | (j == NN - 1) | (xm.z > 0.5f);
        unsigned us = bf16_st(dir ? xm.w : 0.0f);
        uw[c >> 1] |= us << ((c & 1) * 16);
        mw |= (dir ? 0u : 1u) << (c * 8);

        float rr = xm.x * w0 + xm.y * w1 + bb0;
        float ys = (float)j * (1.0f / 511.0f);
        float dd = fminf(dx, fminf(ys, 1.0f - ys));
        float ww = fminf(fmaxf(dd * (1.0f / DELTA_F), 0.0f), 1.0f);
        if (xm.z > 0.5f) ww = 0.0f;
        unsigned ps = bf16_st(ww * rr);
        pw[c >> 1] |= ps << ((c & 1) * 16);
    }
    *(uint2*)(u + idx)    = make_uint2(uw[0], uw[1]);
    *(unsigned*)(cmask + idx) = mw;
    *(uint2*)(pre + idx)  = make_uint2(pw[0], pw[1]);
}

// ---------------------------------------------------------------------------
// Register-tile temporal-blocked stencil, 4x4 cells/thread, bf16 state,
// fully vectorized direct I/O (uint2 per row, no LDS staging).
// 16x16 threads own a 64x64 tile (48x48 output, halo 8 >= ITERS).
// No load clamping: edge blocks read fictitious (guarded, finite) halo data;
// the in-domain Dirichlet edge rows are frozen and the 5-point stencil
// cannot jump them, so garbage never reaches the valid center.
// ---------------------------------------------------------------------------
template<int ITERS, bool FINAL>
__global__ __launch_bounds__(256, 4) void stencil_kernel(
    const unsigned short* __restrict__ uin,
    unsigned short* __restrict__ uout,      // bf16 dest (non-final)
    float* __restrict__ fout,               // f32 dest (final)
    const unsigned char* __restrict__ cmask,
    const unsigned short* __restrict__ pre,
    const float* __restrict__ logit,
    const float* __restrict__ y_mean,
    const float* __restrict__ y_std)
{
    __shared__ float xup[2][PT][256];   // thread row 0 (for tr-1)
    __shared__ float xdn[2][PT][256];   // thread row PT-1 (for tr+1)

    const int b   = blockIdx.z;
    const int oy  = min((int)blockIdx.y * OUT, NN - OUT);
    const int ox  = min((int)blockIdx.x * OUT, NN - OUT);
    const int tid = threadIdx.x;
    const int tr  = tid >> 4;
    const int tc  = tid & 15;
    const int R0  = tr * PT;
    const int C0  = tc * PT;
    const int ty0 = oy - HALO;
    const int tx0 = ox - HALO;

    const size_t slab = (size_t)b * NN * NN;
    const unsigned short* ub = uin + slab;
    const unsigned char*  cb = cmask + slab;

    float u[PT][PT];
    float cf[PT][PT];   // 1.0 = fluid (update), 0.0 = Dirichlet/frozen

    // ---- setup: vectorized load, one uint2(u) + uint(cmask) per row ----
#pragma unroll
    for (int r = 0; r < PT; ++r) {
        int ty  = R0 + r;
        int off = (ty0 + ty) * NN + tx0 + C0;   // may be <0 / >end: guarded
        uint2 v = *(const uint2*)(ub + off);
        unsigned mm = *(const unsigned*)(cb + off);
        unsigned uwv[2] = {v.x, v.y};
#pragma unroll
        for (int c = 0; c < PT; ++c) {
            unsigned hw = (uwv[c >> 1] >> ((c & 1) * 16)) & 0xFFFFu;
            u[r][c] = __uint_as_float(hw << 16);
            unsigned m = (mm >> (c * 8)) & 0xFFu;
            int tx = C0 + c;
            bool ring = (ty == 0) | (ty == TILE - 1) | (tx == 0) | (tx == TILE - 1);
            cf[r][c] = (ring || m == 0u) ? 0.0f : 1.0f;
        }
    }

    const int tup = (tid >= 16)  ? tid - 16 : tid;   // clamped neighbor indices
    const int tdn = (tid < 240)  ? tid + 16 : tid;

    // ---- ITERS fused Jacobi iterations, all in registers ----
#pragma unroll 1
    for (int t = 0; t < ITERS; ++t) {
        const int pb = t & 1;
#pragma unroll
        for (int w = 0; w < PT; ++w) {
            xup[pb][w][tid] = u[0][w];
            xdn[pb][w][tid] = u[PT - 1][w];
        }
        float lsh[PT], rsh[PT];
#pragma unroll
        for (int r = 0; r < PT; ++r) {
            lsh[r] = dpp_shr1(u[r][PT - 1]);
            rsh[r] = dpp_shl1(u[r][0]);
        }
        __syncthreads();
        float th[PT], bh[PT];
#pragma unroll
        for (int w = 0; w < PT; ++w) {
            th[w] = xdn[pb][w][tup];   // garbage for tr==0: ring cf=0 kills it
            bh[w] = xup[pb][w][tdn];   // garbage for tr==15: ring cf=0 kills it
        }
        float prow[PT];
#pragma unroll
        for (int c = 0; c < PT; ++c) prow[c] = th[c];
#pragma unroll
        for (int r = 0; r < PT; ++r) {
            float orow[PT];
#pragma unroll
            for (int c = 0; c < PT; ++c) orow[c] = u[r][c];
#pragma unroll
            for (int c = 0; c < PT; ++c) {
                float up = prow[c];
                float dn = (r < PT - 1) ? u[r + 1][c] : bh[c];
                float lf = (c > 0)      ? orow[c - 1] : lsh[r];
                float rt = (c < PT - 1) ? orow[c + 1] : rsh[r];
                float s  = (up + dn) + (lf + rt);
                float od = orow[c];
                float tq = __builtin_fmaf(0.25f, s, -od);
                u[r][c]  = __builtin_fmaf(cf[r][c], tq, od);
            }
#pragma unroll
            for (int c = 0; c < PT; ++c) prow[c] = orow[c];
        }
    }

    // ---- store center 48x48: threads (tr,tc) in [2,14)^2, vectorized ----
    const bool inner = (tr >= 2) & (tr < 14) & (tc >= 2) & (tc < 14);
    if (!FINAL) {
        if (inner) {
            unsigned short* og = uout + slab;
            int gcol = ox + C0 - HALO;
#pragma unroll
            for (int r = 0; r < PT; ++r) {
                int grow = oy + R0 + r - HALO;
                unsigned a = bf16_st(u[r][0]) | ((unsigned)bf16_st(u[r][1]) << 16);
                unsigned d = bf16_st(u[r][2]) | ((unsigned)bf16_st(u[r][3]) << 16);
                *(uint2*)(og + grow * NN + gcol) = make_uint2(a, d);
            }
        }
    } else {
        if (inner) {
            float* og = fout + slab;
            const unsigned short* pg = pre + slab;
            float rs  = 0.25f / (1.0f + expf(-logit[0]));
            float ym  = y_mean[0];
            float inv = 1.0f / (y_std[0] + EPS_F);
            int gcol = ox + C0 - HALO;
#pragma unroll
            for (int r = 0; r < PT; ++r) {
                int grow = oy + R0 + r - HALO;
                uint2 pv = *(const uint2*)(pg + grow * NN + gcol);
                unsigned pwv[2] = {pv.x, pv.y};
                float4 o;
                float* op = &o.x;
#pragma unroll
                for (int c = 0; c < PT; ++c) {
                    float e = (u[r][c] - ym) * inv;
                    float p = bf16_ld((unsigned short)((pwv[c >> 1] >> ((c & 1) * 16)) & 0xFFFFu));
                    op[c] = __builtin_fmaf(rs, p, e);
                }
                *(float4*)(og + grow * NN + gcol) = o;
            }
        }
    }
}

// ---------------------------------------------------------------------------
extern "C" void kernel_launch(void* const* d_in, const int* in_sizes, int n_in,
                              void* d_out, int out_size, void* d_ws, size_t ws_size,
                              hipStream_t stream)
{
    const float* x_mix  = (const float*)d_in[0];
    const float* w_back = (const float*)d_in[1];
    const float* b_back = (const float*)d_in[2];
    const float* logit  = (const float*)d_in[3];
    const float* y_mean = (const float*)d_in[4];
    const float* y_std  = (const float*)d_in[5];

    float* out = (float*)d_out;

    // Workspace: [GUARD][u_a 2B][cmask 1B][u_b 2B][pre 2B] — halo vector
    // loads may run up to ~8.5 KB past either end of u_a/u_b/cmask; every
    // such access lands in an adjacent defined region or the guard, and all
    // bit patterns there decode to finite floats.
    char* ws = (char*)d_ws;
    unsigned short* u_a   = (unsigned short*)(ws + GUARD);
    unsigned char*  cmask = (unsigned char*) (ws + GUARD + (size_t)TOTAL * 2);
    unsigned short* u_b   = (unsigned short*)(ws + GUARD + (size_t)TOTAL * 3);
    unsigned short* pre   = (unsigned short*)(ws + GUARD + (size_t)TOTAL * 5);

    init_kernel<<<TOTAL / 4 / 256, 256, 0, stream>>>(
        (const float4*)x_mix, u_a, cmask, pre, w_back, b_back);

    // 50 iters = 6 launches x 8 + 1 launch x 2 (fused epilogue).
    // Chain: a->b, b->a, a->b, b->a, a->b, b->a, then FINAL a->out.
    dim3 sgrid((NN + OUT - 1) / OUT, (NN + OUT - 1) / OUT, BB);  // 11x11x16
    stencil_kernel<8, false><<<sgrid, 256, 0, stream>>>(u_a, u_b, out, cmask,
        pre, logit, y_mean, y_std);
    stencil_kernel<8, false><<<sgrid, 256, 0, stream>>>(u_b, u_a, out, cmask,
        pre, logit, y_mean, y_std);
    stencil_kernel<8, false><<<sgrid, 256, 0, stream>>>(u_a, u_b, out, cmask,
        pre, logit, y_mean, y_std);
    stencil_kernel<8, false><<<sgrid, 256, 0, stream>>>(u_b, u_a, out, cmask,
        pre, logit, y_mean, y_std);
    stencil_kernel<8, false><<<sgrid, 256, 0, stream>>>(u_a, u_b, out, cmask,
        pre, logit, y_mean, y_std);
    stencil_kernel<8, false><<<sgrid, 256, 0, stream>>>(u_b, u_a, out, cmask,
        pre, logit, y_mean, y_std);
    stencil_kernel<2, true><<<sgrid, 256, 0, stream>>>(u_a, u_b, out, cmask,
        pre, logit, y_mean, y_std);
}

// Round 11
// 131.089 us; speedup vs baseline: 1.3902x; 1.0038x over previous
//
#include <hip/hip_runtime.h>
#include <hip/hip_cooperative_groups.h>
#include <math.h>

namespace cg = cooperative_groups;

#define NN 512
#define BB 16
#define TOTAL (BB * NN * NN)   // 4,194,304 cells
#define EPS_F 1e-5f
#define DELTA_F 0.05f
#define GUARD 16384             // bytes; worst ring over/under-run ~8.2 KB

// cooperative-kernel geometry
#define HALO 8
#define TILE 80                 // register tile (80x80), valid center 64x64
#define OUT  64
#define PT   5                  // cells per thread per dim (80/16)
#define PHASES 6                // 6*8 + 2 = 50 iterations

// fallback (round-9) geometry
#define FB_TILE 64
#define FB_OUT  48
#define FB_PT   4

// bf16 helpers (storage only; all math in f32)
__device__ __forceinline__ float bf16_ld(unsigned short h) {
    return __uint_as_float((unsigned)h << 16);
}
__device__ __forceinline__ unsigned short bf16_st(float f) {
    unsigned b = __float_as_uint(f);
    return (unsigned short)((b + 0x7FFFu + ((b >> 16) & 1u)) >> 16);  // RNE
}

// lane gets lane-1 (within each 16-lane DPP row); boundary lanes -> 0
__device__ __forceinline__ float dpp_shr1(float x) {
    int r = __builtin_amdgcn_update_dpp(0, __float_as_int(x), 0x111, 0xf, 0xf, true);
    return __int_as_float(r);
}
// lane gets lane+1; boundary lanes -> 0
__device__ __forceinline__ float dpp_shl1(float x) {
    int r = __builtin_amdgcn_update_dpp(0, __float_as_int(x), 0x101, 0xf, 0xf, true);
    return __int_as_float(r);
}

// ---------------------------------------------------------------------------
// Init (4 cells/thread, vectorized): u0(bf16) = dir ? bc : 0 ;
// cmask(u8) = fluid ; pre(bf16) = w_outer * [geom<=0.5] * (x·w_back + b)
// ---------------------------------------------------------------------------
__global__ __launch_bounds__(256) void init_kernel(
    const float4* __restrict__ xm4,
    unsigned short* __restrict__ u,
    unsigned char* __restrict__ cmask,
    unsigned short* __restrict__ pre,
    const float* __restrict__ w_back,
    const float* __restrict__ b_back)
{
    int g = blockIdx.x * 256 + threadIdx.x;      // 0 .. TOTAL/4-1
    int idx = g * 4;
    int j0 = idx & (NN - 1);
    int i  = (idx >> 9) & (NN - 1);
    float w0 = w_back[0], w1 = w_back[1], bb0 = b_back[0];
    float xs = (float)i * (1.0f / 511.0f);
    float dx = fminf(xs, 1.0f - xs);
    bool iedge = (i == 0) | (i == NN - 1);

    unsigned uw[2] = {0u, 0u};
    unsigned mw = 0u;
    unsigned pw[2] = {0u, 0u};
#pragma unroll
    for (int c = 0; c < 4; ++c) {
        float4 xm = xm4[idx + c];
        int j = j0 + c;
        bool dir = iedge | (j == 0) | (j == NN - 1) | (xm.z > 0.5f);
        unsigned us = bf16_st(dir ? xm.w : 0.0f);
        uw[c >> 1] |= us << ((c & 1) * 16);
        mw |= (dir ? 0u : 1u) << (c * 8);

        float rr = xm.x * w0 + xm.y * w1 + bb0;
        float ys = (float)j * (1.0f / 511.0f);
        float dd = fminf(dx, fminf(ys, 1.0f - ys));
        float ww = fminf(fmaxf(dd * (1.0f / DELTA_F), 0.0f), 1.0f);
        if (xm.z > 0.5f) ww = 0.0f;
        unsigned ps = bf16_st(ww * rr);
        pw[c >> 1] |= ps << ((c & 1) * 16);
    }
    *(uint2*)(u + idx)        = make_uint2(uw[0], uw[1]);
    *(unsigned*)(cmask + idx) = mw;
    *(uint2*)(pre + idx)      = make_uint2(pw[0], pw[1]);
}

// ---------------------------------------------------------------------------
// Cooperative kernel: 50 Jacobi iterations with state resident in registers.
// 1024 blocks = 4/CU. Per phase (8 iters): register Jacobi (LDS/DPP halo);
// then publish the 8-deep frame of the valid 64x64 center and re-read the
// 8-deep ring via AGENT-SCOPE ATOMICS (coherent across non-coherent XCD L2s,
// per Guideline 16), double-buffered across grid.sync()s.
// ---------------------------------------------------------------------------
__global__ __launch_bounds__(256, 4) void coop_kernel(
    unsigned short* u_a,                    // initial state + odd-phase strips
    unsigned short* u_b,                    // even-phase strips
    const unsigned char* cmask,
    const unsigned short* pre,
    float* fout,
    const float* logit,
    const float* y_mean,
    const float* y_std)
{
    __shared__ __align__(16) char shm[20480];
    float (*xup)[PT][256] = reinterpret_cast<float(*)[PT][256]>(shm);          // [2][PT][256]
    float (*xdn)[PT][256] = reinterpret_cast<float(*)[PT][256]>(shm + 10240);
    float* fr     = (float*)shm;   // 1792 f32 frame stage   (phase-disjoint)
    float* rg     = (float*)shm;   // 2304 f32 ring stage    (phase-disjoint)
    float* fstage = (float*)shm;   // 4096 f32 epilogue      (phase-disjoint)

    const int b   = blockIdx.z;
    const int oy  = blockIdx.y * OUT;
    const int ox  = blockIdx.x * OUT;
    const int tid = threadIdx.x;
    const int tr  = tid >> 4;
    const int tc  = tid & 15;
    const int R0  = tr * PT;
    const int C0  = tc * PT;
    const int slab = b * NN * NN;

    float u[PT][PT];
    float cf[PT][PT];   // 1.0 = fluid (update), 0.0 = Dirichlet/frozen

    // ---- one-time setup: 80x80 tile load (guarded, no clamp) ----
#pragma unroll
    for (int r = 0; r < PT; ++r) {
        int ty = R0 + r;
        int gy = oy - HALO + ty;
#pragma unroll
        for (int c = 0; c < PT; ++c) {
            int tx  = C0 + c;
            int gx  = ox - HALO + tx;
            int off = slab + gy * NN + gx;      // may stray into guard: finite
            u[r][c] = bf16_ld(u_a[off]);
            unsigned m = cmask[off];
            bool ring = (ty == 0) | (ty == TILE - 1) | (tx == 0) | (tx == TILE - 1);
            cf[r][c] = (ring || m == 0u) ? 0.0f : 1.0f;
        }
    }

    const int tup = (tid >= 16)  ? tid - 16 : tid;
    const int tdn = (tid < 240)  ? tid + 16 : tid;

    auto iterate = [&](int iters) {
#pragma unroll 1
        for (int t = 0; t < iters; ++t) {
            const int pb = t & 1;
#pragma unroll
            for (int w = 0; w < PT; ++w) {
                xup[pb][w][tid] = u[0][w];
                xdn[pb][w][tid] = u[PT - 1][w];
            }
            float lsh[PT], rsh[PT];
#pragma unroll
            for (int r = 0; r < PT; ++r) {
                lsh[r] = dpp_shr1(u[r][PT - 1]);
                rsh[r] = dpp_shl1(u[r][0]);
            }
            __syncthreads();
            float th[PT], bh[PT];
#pragma unroll
            for (int w = 0; w < PT; ++w) {
                th[w] = xdn[pb][w][tup];   // garbage for tr==0: ring cf=0 kills it
                bh[w] = xup[pb][w][tdn];   // garbage for tr==15: ring cf=0 kills it
            }
            float prow[PT];
#pragma unroll
            for (int c = 0; c < PT; ++c) prow[c] = th[c];
#pragma unroll
            for (int r = 0; r < PT; ++r) {
                float orow[PT];
#pragma unroll
                for (int c = 0; c < PT; ++c) orow[c] = u[r][c];
#pragma unroll
                for (int c = 0; c < PT; ++c) {
                    float up = prow[c];
                    float dn = (r < PT - 1) ? u[r + 1][c] : bh[c];
                    float lf = (c > 0)      ? orow[c - 1] : lsh[r];
                    float rt = (c < PT - 1) ? orow[c + 1] : rsh[r];
                    float s  = (up + dn) + (lf + rt);
                    float od = orow[c];
                    float tq = __builtin_fmaf(0.25f, s, -od);
                    u[r][c]  = __builtin_fmaf(cf[r][c], tq, od);
                }
#pragma unroll
                for (int c = 0; c < PT; ++c) prow[c] = orow[c];
            }
        }
    };

    cg::grid_group grid = cg::this_grid();

#pragma unroll 1
    for (int p = 0; p < PHASES; ++p) {
        iterate(8);
        __syncthreads();   // drain last iteration's LDS reads before reuse
        // ---- stage my center frame (8-deep band of [0,64)^2) into LDS ----
#pragma unroll
        for (int r = 0; r < PT; ++r) {
            int cy = R0 + r - HALO;
#pragma unroll
            for (int c = 0; c < PT; ++c) {
                int cx = C0 + c - HALO;
                if ((unsigned)cy < 64u && (unsigned)cx < 64u) {
                    if ((cy < 8) | (cy >= 56) | (cx < 8) | (cx >= 56)) {
                        int li = (cy < 8)   ? cy * 64 + cx
                               : (cy >= 56) ? 512 + (cy - 56) * 64 + cx
                               : (cx < 8)   ? 1024 + (cy - 8) * 8 + cx
                               :              1408 + (cy - 8) * 8 + (cx - 56);
                        fr[li] = u[r][c];
                    }
                }
            }
        }
        __syncthreads();
        unsigned short* buf = (p & 1) ? u_a : u_b;   // double-buffered strips
        // ---- publish 896 bf16-pairs via agent-scope atomic stores ----
#pragma unroll
        for (int k0 = 0; k0 < 4; ++k0) {
            int pidx = tid + k0 * 256;
            if (pidx < 896) {
                int gy, gx, li;
                if (pidx < 256)      { int pr = pidx >> 5, pc = pidx & 31;
                    gy = pr;      gx = 2 * pc;      li = pr * 64 + 2 * pc; }
                else if (pidx < 512) { int q = pidx - 256; int pr = q >> 5, pc = q & 31;
                    gy = 56 + pr; gx = 2 * pc;      li = 512 + pr * 64 + 2 * pc; }
                else if (pidx < 704) { int q = pidx - 512; int pr = q >> 2, pc = q & 3;
                    gy = 8 + pr;  gx = 2 * pc;      li = 1024 + pr * 8 + 2 * pc; }
                else                 { int q = pidx - 704; int pr = q >> 2, pc = q & 3;
                    gy = 8 + pr;  gx = 56 + 2 * pc; li = 1408 + pr * 8 + 2 * pc; }
                unsigned val = (unsigned)bf16_st(fr[li]) |
                               ((unsigned)bf16_st(fr[li + 1]) << 16);
                unsigned* dst = (unsigned*)(buf + slab + (oy + gy) * NN + (ox + gx));
                __hip_atomic_store(dst, val, __ATOMIC_RELEASE, __HIP_MEMORY_SCOPE_AGENT);
            }
        }
        __threadfence();
        grid.sync();
        // ---- read 1152 ring pairs via agent-scope atomic loads into LDS ----
#pragma unroll
        for (int k0 = 0; k0 < 5; ++k0) {
            int pidx = tid + k0 * 256;
            if (pidx < 1152) {
                int gy, gx, li;
                if (pidx < 320)      { int pr = pidx / 40, pc = pidx - pr * 40;
                    gy = -8 + pr; gx = -8 + 2 * pc; li = pr * 80 + 2 * pc; }
                else if (pidx < 640) { int q = pidx - 320; int pr = q / 40, pc = q - pr * 40;
                    gy = 64 + pr; gx = -8 + 2 * pc; li = 640 + pr * 80 + 2 * pc; }
                else if (pidx < 896) { int q = pidx - 640; int pr = q >> 2, pc = q & 3;
                    gy = pr;      gx = -8 + 2 * pc; li = 1280 + pr * 8 + 2 * pc; }
                else                 { int q = pidx - 896; int pr = q >> 2, pc = q & 3;
                    gy = pr;      gx = 64 + 2 * pc; li = 1792 + pr * 8 + 2 * pc; }
                const unsigned* src = (const unsigned*)(buf + slab + (oy + gy) * NN + (ox + gx));
                unsigned v = __hip_atomic_load(src, __ATOMIC_ACQUIRE, __HIP_MEMORY_SCOPE_AGENT);
                rg[li]     = bf16_ld((unsigned short)(v & 0xFFFFu));
                rg[li + 1] = bf16_ld((unsigned short)(v >> 16));
            }
        }
        __syncthreads();
        // ---- unpack my ring cells from LDS ----
#pragma unroll
        for (int r = 0; r < PT; ++r) {
            int ty = R0 + r;
#pragma unroll
            for (int c = 0; c < PT; ++c) {
                int tx = C0 + c;
                if ((ty < HALO) | (ty >= TILE - HALO) | (tx < HALO) | (tx >= TILE - HALO)) {
                    int li = (ty < 8)   ? ty * 80 + tx
                           : (ty >= 72) ? 640 + (ty - 72) * 80 + tx
                           : (tx < 8)   ? 1280 + (ty - 8) * 8 + tx
                           :              1792 + (ty - 8) * 8 + (tx - 72);
                    u[r][c] = rg[li];
                }
            }
        }
        __syncthreads();   // rg consumed before next iterate overwrites shm
    }

    iterate(2);   // total 50

    // ---- fused epilogue: stage f32 center through LDS, coalesced store ----
    __syncthreads();
    {
        float rs  = 0.25f / (1.0f + expf(-logit[0]));
        float ym  = y_mean[0];
        float inv = 1.0f / (y_std[0] + EPS_F);
        const unsigned short* pg = pre + slab;
#pragma unroll
        for (int r = 0; r < PT; ++r) {
            int cy = R0 + r - HALO;
#pragma unroll
            for (int c = 0; c < PT; ++c) {
                int cx = C0 + c - HALO;
                if ((unsigned)cy < (unsigned)OUT && (unsigned)cx < (unsigned)OUT) {
                    float e = (u[r][c] - ym) * inv;
                    float pp = bf16_ld(pg[(oy + cy) * NN + ox + cx]);
                    fstage[cy * OUT + cx] = __builtin_fmaf(rs, pp, e);
                }
            }
        }
    }
    __syncthreads();
    {
        float* og = fout + slab;
#pragma unroll
        for (int k0 = 0; k0 < 4; ++k0) {
            int k = tid + k0 * 256;
            int r = k >> 4, c = k & 15;
            *(float4*)(og + (oy + r) * NN + ox + c * 4) =
                *(const float4*)(fstage + r * OUT + c * 4);
        }
    }
}

// ---------------------------------------------------------------------------
// Fallback: round-9 multi-launch stencil (proven passing at 131.6 us).
// ---------------------------------------------------------------------------
template<int ITERS, bool FINAL>
__global__ __launch_bounds__(256, 4) void stencil_kernel(
    const unsigned short* __restrict__ uin,
    unsigned short* __restrict__ uout,
    float* __restrict__ fout,
    const unsigned char* __restrict__ cmask,
    const unsigned short* __restrict__ pre,
    const float* __restrict__ logit,
    const float* __restrict__ y_mean,
    const float* __restrict__ y_std)
{
    __shared__ float xup[2][FB_PT][256];
    __shared__ float xdn[2][FB_PT][256];

    const int b   = blockIdx.z;
    const int oy  = min((int)blockIdx.y * FB_OUT, NN - FB_OUT);
    const int ox  = min((int)blockIdx.x * FB_OUT, NN - FB_OUT);
    const int tid = threadIdx.x;
    const int tr  = tid >> 4;
    const int tc  = tid & 15;
    const int R0  = tr * FB_PT;
    const int C0  = tc * FB_PT;
    const int ty0 = oy - HALO;
    const int tx0 = ox - HALO;

    const size_t slab = (size_t)b * NN * NN;
    const unsigned short* ub = uin + slab;
    const unsigned char*  cb = cmask + slab;

    float u[FB_PT][FB_PT];
    float cf[FB_PT][FB_PT];

#pragma unroll
    for (int r = 0; r < FB_PT; ++r) {
        int ty  = R0 + r;
        int off = (ty0 + ty) * NN + tx0 + C0;
        uint2 v = *(const uint2*)(ub + off);
        unsigned mm = *(const unsigned*)(cb + off);
        unsigned uwv[2] = {v.x, v.y};
#pragma unroll
        for (int c = 0; c < FB_PT; ++c) {
            unsigned hw = (uwv[c >> 1] >> ((c & 1) * 16)) & 0xFFFFu;
            u[r][c] = __uint_as_float(hw << 16);
            unsigned m = (mm >> (c * 8)) & 0xFFu;
            int tx = C0 + c;
            bool ring = (ty == 0) | (ty == FB_TILE - 1) | (tx == 0) | (tx == FB_TILE - 1);
            cf[r][c] = (ring || m == 0u) ? 0.0f : 1.0f;
        }
    }

    const int tup = (tid >= 16)  ? tid - 16 : tid;
    const int tdn = (tid < 240)  ? tid + 16 : tid;

#pragma unroll 1
    for (int t = 0; t < ITERS; ++t) {
        const int pb = t & 1;
#pragma unroll
        for (int w = 0; w < FB_PT; ++w) {
            xup[pb][w][tid] = u[0][w];
            xdn[pb][w][tid] = u[FB_PT - 1][w];
        }
        float lsh[FB_PT], rsh[FB_PT];
#pragma unroll
        for (int r = 0; r < FB_PT; ++r) {
            lsh[r] = dpp_shr1(u[r][FB_PT - 1]);
            rsh[r] = dpp_shl1(u[r][0]);
        }
        __syncthreads();
        float th[FB_PT], bh[FB_PT];
#pragma unroll
        for (int w = 0; w < FB_PT; ++w) {
            th[w] = xdn[pb][w][tup];
            bh[w] = xup[pb][w][tdn];
        }
        float prow[FB_PT];
#pragma unroll
        for (int c = 0; c < FB_PT; ++c) prow[c] = th[c];
#pragma unroll
        for (int r = 0; r < FB_PT; ++r) {
            float orow[FB_PT];
#pragma unroll
            for (int c = 0; c < FB_PT; ++c) orow[c] = u[r][c];
#pragma unroll
            for (int c = 0; c < FB_PT; ++c) {
                float up = prow[c];
                float dn = (r < FB_PT - 1) ? u[r + 1][c] : bh[c];
                float lf = (c > 0)         ? orow[c - 1] : lsh[r];
                float rt = (c < FB_PT - 1) ? orow[c + 1] : rsh[r];
                float s  = (up + dn) + (lf + rt);
                float od = orow[c];
                float tq = __builtin_fmaf(0.25f, s, -od);
                u[r][c]  = __builtin_fmaf(cf[r][c], tq, od);
            }
#pragma unroll
            for (int c = 0; c < FB_PT; ++c) prow[c] = orow[c];
        }
    }

    const bool inner = (tr >= 2) & (tr < 14) & (tc >= 2) & (tc < 14);
    if (!FINAL) {
        if (inner) {
            unsigned short* og = uout + slab;
            int gcol = ox + C0 - HALO;
#pragma unroll
            for (int r = 0; r < FB_PT; ++r) {
                int grow = oy + R0 + r - HALO;
                unsigned a = bf16_st(u[r][0]) | ((unsigned)bf16_st(u[r][1]) << 16);
                unsigned d = bf16_st(u[r][2]) | ((unsigned)bf16_st(u[r][3]) << 16);
                *(uint2*)(og + grow * NN + gcol) = make_uint2(a, d);
            }
        }
    } else {
        if (inner) {
            float* og = fout + slab;
            const unsigned short* pg = pre + slab;
            float rs  = 0.25f / (1.0f + expf(-logit[0]));
            float ym  = y_mean[0];
            float inv = 1.0f / (y_std[0] + EPS_F);
            int gcol = ox + C0 - HALO;
#pragma unroll
            for (int r = 0; r < FB_PT; ++r) {
                int grow = oy + R0 + r - HALO;
                uint2 pv = *(const uint2*)(pg + grow * NN + gcol);
                unsigned pwv[2] = {pv.x, pv.y};
                float4 o;
                float* op = &o.x;
#pragma unroll
                for (int c = 0; c < FB_PT; ++c) {
                    float e = (u[r][c] - ym) * inv;
                    float p = bf16_ld((unsigned short)((pwv[c >> 1] >> ((c & 1) * 16)) & 0xFFFFu));
                    op[c] = __builtin_fmaf(rs, p, e);
                }
                *(float4*)(og + grow * NN + gcol) = o;
            }
        }
    }
}

// ---------------------------------------------------------------------------
extern "C" void kernel_launch(void* const* d_in, const int* in_sizes, int n_in,
                              void* d_out, int out_size, void* d_ws, size_t ws_size,
                              hipStream_t stream)
{
    const float* x_mix  = (const float*)d_in[0];
    const float* w_back = (const float*)d_in[1];
    const float* b_back = (const float*)d_in[2];
    const float* logit  = (const float*)d_in[3];
    const float* y_mean = (const float*)d_in[4];
    const float* y_std  = (const float*)d_in[5];

    float* out = (float*)d_out;

    // Workspace: [GUARD][u_a 2B][cmask 1B][u_b 2B][pre 2B]
    char* ws = (char*)d_ws;
    unsigned short* u_a   = (unsigned short*)(ws + GUARD);
    unsigned char*  cmask = (unsigned char*) (ws + GUARD + (size_t)TOTAL * 2);
    unsigned short* u_b   = (unsigned short*)(ws + GUARD + (size_t)TOTAL * 3);
    unsigned short* pre   = (unsigned short*)(ws + GUARD + (size_t)TOTAL * 5);

    init_kernel<<<TOTAL / 4 / 256, 256, 0, stream>>>(
        (const float4*)x_mix, u_a, cmask, pre, w_back, b_back);

    // Prefer the cooperative single-kernel path; verify residency first and
    // fall back to the proven multi-launch chain on any failure.
    bool coop_ok = false;
    int maxB = 0;
    hipError_t qe = hipOccupancyMaxActiveBlocksPerMultiprocessor(&maxB, coop_kernel, 256, 0);
    if (qe == hipSuccess && maxB >= 4) {
        void* args[] = { (void*)&u_a, (void*)&u_b, (void*)&cmask, (void*)&pre,
                         (void*)&out, (void*)&logit, (void*)&y_mean, (void*)&y_std };
        hipError_t le = hipLaunchCooperativeKernel((const void*)coop_kernel,
                                                   dim3(NN / OUT, NN / OUT, BB),
                                                   dim3(256), args, 0, stream);
        if (le == hipSuccess) coop_ok = true;
        else (void)hipGetLastError();
    } else {
        (void)hipGetLastError();
    }

    if (!coop_ok) {
        dim3 sgrid((NN + FB_OUT - 1) / FB_OUT, (NN + FB_OUT - 1) / FB_OUT, BB);
        stencil_kernel<8, false><<<sgrid, 256, 0, stream>>>(u_a, u_b, out, cmask,
            pre, logit, y_mean, y_std);
        stencil_kernel<8, false><<<sgrid, 256, 0, stream>>>(u_b, u_a, out, cmask,
            pre, logit, y_mean, y_std);
        stencil_kernel<8, false><<<sgrid, 256, 0, stream>>>(u_a, u_b, out, cmask,
            pre, logit, y_mean, y_std);
        stencil_kernel<8, false><<<sgrid, 256, 0, stream>>>(u_b, u_a, out, cmask,
            pre, logit, y_mean, y_std);
        stencil_kernel<8, false><<<sgrid, 256, 0, stream>>>(u_a, u_b, out, cmask,
            pre, logit, y_mean, y_std);
        stencil_kernel<8, false><<<sgrid, 256, 0, stream>>>(u_b, u_a, out, cmask,
            pre, logit, y_mean, y_std);
        stencil_kernel<2, true><<<sgrid, 256, 0, stream>>>(u_a, u_b, out, cmask,
            pre, logit, y_mean, y_std);
    }
}

// Round 12
// 130.778 us; speedup vs baseline: 1.3935x; 1.0024x over previous
//
#include <hip/hip_runtime.h>
#include <math.h>

#define NN 512
#define BB 16
#define TOTAL (BB * NN * NN)   // 4,194,304 cells
#define EPS_F 1e-5f
#define DELTA_F 0.05f

#define HALO 8
#define TILE 64                 // register tile (64x64), output 48x48
#define OUT  48
#define PT   4                  // cells per thread per dim (64/16)
#define GUARD 16384             // bytes; halo over/under-run is <= ~8.5 KB

// bf16 helpers (storage only; all math in f32)
__device__ __forceinline__ float bf16_ld(unsigned short h) {
    return __uint_as_float((unsigned)h << 16);
}
__device__ __forceinline__ unsigned short bf16_st(float f) {
    unsigned b = __float_as_uint(f);
    return (unsigned short)((b + 0x7FFFu + ((b >> 16) & 1u)) >> 16);  // RNE
}

// lane gets lane-1 (within each 16-lane DPP row); boundary lanes -> 0
__device__ __forceinline__ float dpp_shr1(float x) {
    int r = __builtin_amdgcn_update_dpp(0, __float_as_int(x), 0x111, 0xf, 0xf, true);
    return __int_as_float(r);
}
// lane gets lane+1; boundary lanes -> 0
__device__ __forceinline__ float dpp_shl1(float x) {
    int r = __builtin_amdgcn_update_dpp(0, __float_as_int(x), 0x101, 0xf, 0xf, true);
    return __int_as_float(r);
}

// ---------------------------------------------------------------------------
// Init (4 cells/thread, vectorized): u0(bf16) = dir ? bc : 0 ;
// cmask(u8) = fluid ; pre(bf16) = w_outer * [geom<=0.5] * (x·w_back + b)
// ---------------------------------------------------------------------------
__global__ __launch_bounds__(256) void init_kernel(
    const float4* __restrict__ xm4,
    unsigned short* __restrict__ u,
    unsigned char* __restrict__ cmask,
    unsigned short* __restrict__ pre,
    const float* __restrict__ w_back,
    const float* __restrict__ b_back)
{
    int g = blockIdx.x * 256 + threadIdx.x;      // 0 .. TOTAL/4-1
    int idx = g * 4;
    int j0 = idx & (NN - 1);
    int i  = (idx >> 9) & (NN - 1);
    float w0 = w_back[0], w1 = w_back[1], bb0 = b_back[0];
    float xs = (float)i * (1.0f / 511.0f);
    float dx = fminf(xs, 1.0f - xs);
    bool iedge = (i == 0) | (i == NN - 1);

    unsigned uw[2] = {0u, 0u};
    unsigned mw = 0u;
    unsigned pw[2] = {0u, 0u};
#pragma unroll
    for (int c = 0; c < 4; ++c) {
        float4 xm = xm4[idx + c];
        int j = j0 + c;
        bool dir = iedge | (j == 0) | (j == NN - 1) | (xm.z > 0.5f);
        unsigned us = bf16_st(dir ? xm.w : 0.0f);
        uw[c >> 1] |= us << ((c & 1) * 16);
        mw |= (dir ? 0u : 1u) << (c * 8);

        float rr = xm.x * w0 + xm.y * w1 + bb0;
        float ys = (float)j * (1.0f / 511.0f);
        float dd = fminf(dx, fminf(ys, 1.0f - ys));
        float ww = fminf(fmaxf(dd * (1.0f / DELTA_F), 0.0f), 1.0f);
        if (xm.z > 0.5f) ww = 0.0f;
        unsigned ps = bf16_st(ww * rr);
        pw[c >> 1] |= ps << ((c & 1) * 16);
    }
    *(uint2*)(u + idx)        = make_uint2(uw[0], uw[1]);
    *(unsigned*)(cmask + idx) = mw;
    *(uint2*)(pre + idx)      = make_uint2(pw[0], pw[1]);
}

// ---------------------------------------------------------------------------
// Register-tile temporal-blocked stencil, 4x4 cells/thread, bf16 state,
// fully vectorized direct I/O. 16x16 threads own a 64x64 tile (48x48 output,
// halo 8 >= ITERS). __launch_bounds__(256,8) pins VGPR<=64 so 8 blocks/CU
// (32 waves) are resident — the extra independent waves fill the barrier/LDS
// latency gaps that capped VALUBusy at ~47% with 4 blocks/CU.
// No load clamping: edge blocks read fictitious (guarded, finite) halo data;
// the in-domain Dirichlet edge rows are frozen and the 5-point stencil
// cannot jump them, so garbage never reaches the valid center.
// ---------------------------------------------------------------------------
template<int ITERS, bool FINAL>
__global__ __launch_bounds__(256, 8) void stencil_kernel(
    const unsigned short* __restrict__ uin,
    unsigned short* __restrict__ uout,      // bf16 dest (non-final)
    float* __restrict__ fout,               // f32 dest (final)
    const unsigned char* __restrict__ cmask,
    const unsigned short* __restrict__ pre,
    const float* __restrict__ logit,
    const float* __restrict__ y_mean,
    const float* __restrict__ y_std)
{
    __shared__ float xup[2][PT][256];   // thread row 0 (for tr-1)
    __shared__ float xdn[2][PT][256];   // thread row PT-1 (for tr+1)

    const int b   = blockIdx.z;
    const int oy  = min((int)blockIdx.y * OUT, NN - OUT);
    const int ox  = min((int)blockIdx.x * OUT, NN - OUT);
    const int tid = threadIdx.x;
    const int tr  = tid >> 4;
    const int tc  = tid & 15;
    const int R0  = tr * PT;
    const int C0  = tc * PT;
    const int ty0 = oy - HALO;
    const int tx0 = ox - HALO;

    const size_t slab = (size_t)b * NN * NN;
    const unsigned short* ub = uin + slab;
    const unsigned char*  cb = cmask + slab;

    float u[PT][PT];
    float cf[PT][PT];   // 1.0 = fluid (update), 0.0 = Dirichlet/frozen

    // ---- setup: vectorized load, one uint2(u) + uint(cmask) per row ----
#pragma unroll
    for (int r = 0; r < PT; ++r) {
        int ty  = R0 + r;
        int off = (ty0 + ty) * NN + tx0 + C0;   // may be <0 / >end: guarded
        uint2 v = *(const uint2*)(ub + off);
        unsigned mm = *(const unsigned*)(cb + off);
        unsigned uwv[2] = {v.x, v.y};
#pragma unroll
        for (int c = 0; c < PT; ++c) {
            unsigned hw = (uwv[c >> 1] >> ((c & 1) * 16)) & 0xFFFFu;
            u[r][c] = __uint_as_float(hw << 16);
            unsigned m = (mm >> (c * 8)) & 0xFFu;
            int tx = C0 + c;
            bool ring = (ty == 0) | (ty == TILE - 1) | (tx == 0) | (tx == TILE - 1);
            cf[r][c] = (ring || m == 0u) ? 0.0f : 1.0f;
        }
    }

    const int tup = (tid >= 16)  ? tid - 16 : tid;   // clamped neighbor indices
    const int tdn = (tid < 240)  ? tid + 16 : tid;

    // ---- ITERS fused Jacobi iterations, all in registers ----
#pragma unroll 1
    for (int t = 0; t < ITERS; ++t) {
        const int pb = t & 1;
#pragma unroll
        for (int w = 0; w < PT; ++w) {
            xup[pb][w][tid] = u[0][w];
            xdn[pb][w][tid] = u[PT - 1][w];
        }
        float lsh[PT], rsh[PT];
#pragma unroll
        for (int r = 0; r < PT; ++r) {
            lsh[r] = dpp_shr1(u[r][PT - 1]);
            rsh[r] = dpp_shl1(u[r][0]);
        }
        __syncthreads();
        float th[PT], bh[PT];
#pragma unroll
        for (int w = 0; w < PT; ++w) {
            th[w] = xdn[pb][w][tup];   // garbage for tr==0: ring cf=0 kills it
            bh[w] = xup[pb][w][tdn];   // garbage for tr==15: ring cf=0 kills it
        }
        float prow[PT];
#pragma unroll
        for (int c = 0; c < PT; ++c) prow[c] = th[c];
#pragma unroll
        for (int r = 0; r < PT; ++r) {
            float orow[PT];
#pragma unroll
            for (int c = 0; c < PT; ++c) orow[c] = u[r][c];
#pragma unroll
            for (int c = 0; c < PT; ++c) {
                float up = prow[c];
                float dn = (r < PT - 1) ? u[r + 1][c] : bh[c];
                float lf = (c > 0)      ? orow[c - 1] : lsh[r];
                float rt = (c < PT - 1) ? orow[c + 1] : rsh[r];
                float s  = (up + dn) + (lf + rt);
                float od = orow[c];
                float tq = __builtin_fmaf(0.25f, s, -od);
                u[r][c]  = __builtin_fmaf(cf[r][c], tq, od);
            }
#pragma unroll
            for (int c = 0; c < PT; ++c) prow[c] = orow[c];
        }
    }

    // ---- store center 48x48: threads (tr,tc) in [2,14)^2, vectorized ----
    const bool inner = (tr >= 2) & (tr < 14) & (tc >= 2) & (tc < 14);
    if (!FINAL) {
        if (inner) {
            unsigned short* og = uout + slab;
            int gcol = ox + C0 - HALO;
#pragma unroll
            for (int r = 0; r < PT; ++r) {
                int grow = oy + R0 + r - HALO;
                unsigned a = bf16_st(u[r][0]) | ((unsigned)bf16_st(u[r][1]) << 16);
                unsigned d = bf16_st(u[r][2]) | ((unsigned)bf16_st(u[r][3]) << 16);
                *(uint2*)(og + grow * NN + gcol) = make_uint2(a, d);
            }
        }
    } else {
        if (inner) {
            float* og = fout + slab;
            const unsigned short* pg = pre + slab;
            float rs  = 0.25f / (1.0f + expf(-logit[0]));
            float ym  = y_mean[0];
            float inv = 1.0f / (y_std[0] + EPS_F);
            int gcol = ox + C0 - HALO;
#pragma unroll
            for (int r = 0; r < PT; ++r) {
                int grow = oy + R0 + r - HALO;
                uint2 pv = *(const uint2*)(pg + grow * NN + gcol);
                unsigned pwv[2] = {pv.x, pv.y};
                float4 o;
                float* op = &o.x;
#pragma unroll
                for (int c = 0; c < PT; ++c) {
                    float e = (u[r][c] - ym) * inv;
                    float p = bf16_ld((unsigned short)((pwv[c >> 1] >> ((c & 1) * 16)) & 0xFFFFu));
                    op[c] = __builtin_fmaf(rs, p, e);
                }
                *(float4*)(og + grow * NN + gcol) = o;
            }
        }
    }
}

// ---------------------------------------------------------------------------
extern "C" void kernel_launch(void* const* d_in, const int* in_sizes, int n_in,
                              void* d_out, int out_size, void* d_ws, size_t ws_size,
                              hipStream_t stream)
{
    const float* x_mix  = (const float*)d_in[0];
    const float* w_back = (const float*)d_in[1];
    const float* b_back = (const float*)d_in[2];
    const float* logit  = (const float*)d_in[3];
    const float* y_mean = (const float*)d_in[4];
    const float* y_std  = (const float*)d_in[5];

    float* out = (float*)d_out;

    // Workspace: [GUARD][u_a 2B][cmask 1B][u_b 2B][pre 2B] — halo vector
    // loads may run up to ~8.5 KB past either end of u_a/u_b/cmask; every
    // such access lands in an adjacent defined region or the guard, and all
    // bit patterns there decode to finite floats.
    char* ws = (char*)d_ws;
    unsigned short* u_a   = (unsigned short*)(ws + GUARD);
    unsigned char*  cmask = (unsigned char*) (ws + GUARD + (size_t)TOTAL * 2);
    unsigned short* u_b   = (unsigned short*)(ws + GUARD + (size_t)TOTAL * 3);
    unsigned short* pre   = (unsigned short*)(ws + GUARD + (size_t)TOTAL * 5);

    init_kernel<<<TOTAL / 4 / 256, 256, 0, stream>>>(
        (const float4*)x_mix, u_a, cmask, pre, w_back, b_back);

    // 50 iters = 6 launches x 8 + 1 launch x 2 (fused epilogue).
    // Chain: a->b, b->a, a->b, b->a, a->b, b->a, then FINAL a->out.
    dim3 sgrid((NN + OUT - 1) / OUT, (NN + OUT - 1) / OUT, BB);  // 11x11x16
    stencil_kernel<8, false><<<sgrid, 256, 0, stream>>>(u_a, u_b, out, cmask,
        pre, logit, y_mean, y_std);
    stencil_kernel<8, false><<<sgrid, 256, 0, stream>>>(u_b, u_a, out, cmask,
        pre, logit, y_mean, y_std);
    stencil_kernel<8, false><<<sgrid, 256, 0, stream>>>(u_a, u_b, out, cmask,
        pre, logit, y_mean, y_std);
    stencil_kernel<8, false><<<sgrid, 256, 0, stream>>>(u_b, u_a, out, cmask,
        pre, logit, y_mean, y_std);
    stencil_kernel<8, false><<<sgrid, 256, 0, stream>>>(u_a, u_b, out, cmask,
        pre, logit, y_mean, y_std);
    stencil_kernel<8, false><<<sgrid, 256, 0, stream>>>(u_b, u_a, out, cmask,
        pre, logit, y_mean, y_std);
    stencil_kernel<2, true><<<sgrid, 256, 0, stream>>>(u_a, u_b, out, cmask,
        pre, logit, y_mean, y_std);
}